// Round 1
// baseline (1960.886 us; speedup 1.0000x reference)
//
#include <hip/hip_runtime.h>
#include <hip/hip_bf16.h>
#include <math.h>

#define CIN   63
#define HWSZ  57600
#define NPIX  460800   // 8*57600

// -------- K0: fold BN into conv_in weights --------
__global__ void k_prep(const float* __restrict__ w_in, const float* __restrict__ b_in,
                       const float* __restrict__ gamma, const float* __restrict__ beta,
                       const float* __restrict__ mean,  const float* __restrict__ var,
                       float* __restrict__ Weff, float* __restrict__ beff) {
    int idx = blockIdx.x * 256 + threadIdx.x;
    if (idx < 7938) {
        int o = idx / 63;
        float s = gamma[o] * rsqrtf(var[o] + 1e-5f);
        Weff[idx] = w_in[idx] * s;
    } else if (idx < 8064) {
        int o = idx - 7938;
        float s = gamma[o] * rsqrtf(var[o] + 1e-5f);
        beff[o] = b_in[o] * s + beta[o] - mean[o] * s;
    }
}

// -------- K1: window attention (branch 0 plain, branch 1 rolled) --------
// one block (64 thr) per 5x5 window; grid = 2*8*48*48 = 36864
__global__ __launch_bounds__(64) void k_win(const float* __restrict__ x,
                                            const float* __restrict__ Weff,
                                            const float* __restrict__ beff,
                                            float* __restrict__ y) {
    int bid = blockIdx.x;
    int branch = bid / 18432;          // 0: ch 0..41 -> y 0..20 ; 1: ch 42..83 -> y 21..41
    int r   = bid - branch * 18432;
    int b   = r / 2304;
    int wrem = r - b * 2304;
    int wi  = wrem / 48;
    int wj  = wrem - wi * 48;
    int tid = threadIdx.x;
    int qb  = branch * 42;
    int ish = branch ? 3 : 0;          // input roll  (-3,-3)
    int osh = branch ? 2 : 0;          // output roll (+2,+2)

    __shared__ float xin[25][64];      // [pixel][in_ch]
    __shared__ float qv[25][44];       // [pixel][0:21=q, 21:42=v]
    __shared__ float S[25][26];        // scores / probs

    // stage x window pixels (all 63 input channels)
    for (int idx = tid; idx < 1575; idx += 64) {
        int ch = idx / 25, p = idx - ch * 25;
        int pr = p / 5, pc = p - pr * 5;
        int ih = (wi * 5 + pr + ish) % 240;
        int iw = (wj * 5 + pc + ish) % 240;
        xin[p][ch] = x[((size_t)(b * 63 + ch)) * HWSZ + ih * 240 + iw];
    }
    __syncthreads();

    // fused projection + BN  (q,v = 42 channels)
    for (int idx = tid; idx < 1050; idx += 64) {
        int p = idx / 42, o = idx - p * 42;
        float acc = beff[qb + o];
        const float* wr = &Weff[(qb + o) * 63];
        #pragma unroll
        for (int ch = 0; ch < 63; ch++) acc += wr[ch] * xin[p][ch];
        qv[p][o] = acc;
    }
    __syncthreads();

    // scores S = q q^T (25x25)
    for (int idx = tid; idx < 625; idx += 64) {
        int i = idx / 25, j = idx - i * 25;
        float s = 0.f;
        #pragma unroll
        for (int c = 0; c < 21; c++) s += qv[i][c] * qv[j][c];
        S[i][j] = s;
    }
    __syncthreads();

    // softmax rows
    if (tid < 25) {
        float m = -1e30f;
        for (int j = 0; j < 25; j++) m = fmaxf(m, S[tid][j]);
        float sum = 0.f;
        for (int j = 0; j < 25; j++) { float e = __expf(S[tid][j] - m); sum += e; S[tid][j] = e; }
        float inv = 1.0f / sum;
        for (int j = 0; j < 25; j++) S[tid][j] *= inv;
    }
    __syncthreads();

    // out = P @ v ; write to y (pixel-major, 64-padded channels)
    for (int idx = tid; idx < 525; idx += 64) {
        int p = idx / 21, o = idx - p * 21;
        float acc = 0.f;
        #pragma unroll
        for (int j = 0; j < 25; j++) acc += S[p][j] * qv[j][21 + o];
        int pr = p / 5, pc = p - pr * 5;
        int oh = (wi * 5 + pr + osh) % 240;
        int ow = (wj * 5 + pc + osh) % 240;
        y[((size_t)b * HWSZ + oh * 240 + ow) * 64 + branch * 21 + o] = acc;
    }
}

// -------- online-softmax attention helper state is inlined in K2/K3 --------

// K2: axial stage 1 (tokens along w, per (b,h) row). grid = 8*240 = 1920, 128 thr.
__global__ __launch_bounds__(128) void k_ax1(const float* __restrict__ x,
                                             const float* __restrict__ Weff,
                                             const float* __restrict__ beff,
                                             float* __restrict__ qws,
                                             float* __restrict__ v1ws) {
    int b = blockIdx.x / 240;
    int h = blockIdx.x - b * 240;
    int tid = threadIdx.x;
    __shared__ float qs[240][24];
    __shared__ float vs[240][24];

    // fused projection (axial channels 84..125), x row staged in registers
    for (int pass = 0; pass < 2; pass++) {
        int w = tid + pass * 128;
        if (w < 240) {
            float xr[63];
            #pragma unroll
            for (int ch = 0; ch < 63; ch++)
                xr[ch] = x[((size_t)(b * 63 + ch)) * HWSZ + h * 240 + w];
            #pragma unroll 1
            for (int o = 0; o < 42; o++) {
                float acc = beff[84 + o];
                const float* wr = &Weff[(84 + o) * 63];
                #pragma unroll
                for (int ch = 0; ch < 63; ch++) acc += wr[ch] * xr[ch];
                if (o < 21) qs[w][o] = acc; else vs[w][o - 21] = acc;
            }
        }
    }
    __syncthreads();

    // persist q transposed ([b][w][h][c]) for stage 2
    for (int pass = 0; pass < 2; pass++) {
        int w = tid + pass * 128;
        if (w < 240) {
            size_t base = (((size_t)b * 240 + w) * 240 + h) * 21;
            #pragma unroll
            for (int c = 0; c < 21; c++) qws[base + c] = qs[w][c];
        }
    }

    // attention: 2 rows per thread (rows t and t+120)
    if (tid < 120) {
        int i0 = tid, i1 = tid + 120;
        float qa[21], qbr[21];
        #pragma unroll
        for (int c = 0; c < 21; c++) { qa[c] = qs[i0][c]; qbr[c] = qs[i1][c]; }
        float m0 = -1e30f, l0 = 0.f, m1 = -1e30f, l1 = 0.f;
        float a0[21], a1[21];
        #pragma unroll
        for (int c = 0; c < 21; c++) { a0[c] = 0.f; a1[c] = 0.f; }
        for (int j = 0; j < 240; j++) {
            float qj[21], vj[21];
            #pragma unroll
            for (int c = 0; c < 21; c++) { qj[c] = qs[j][c]; vj[c] = vs[j][c]; }
            float s0 = 0.f, s1 = 0.f;
            #pragma unroll
            for (int c = 0; c < 21; c++) { s0 += qa[c] * qj[c]; s1 += qbr[c] * qj[c]; }
            if (s0 > m0) {
                float sc = __expf(m0 - s0); l0 *= sc;
                #pragma unroll
                for (int c = 0; c < 21; c++) a0[c] *= sc;
                m0 = s0;
            }
            float p0 = __expf(s0 - m0); l0 += p0;
            #pragma unroll
            for (int c = 0; c < 21; c++) a0[c] += p0 * vj[c];
            if (s1 > m1) {
                float sc = __expf(m1 - s1); l1 *= sc;
                #pragma unroll
                for (int c = 0; c < 21; c++) a1[c] *= sc;
                m1 = s1;
            }
            float p1 = __expf(s1 - m1); l1 += p1;
            #pragma unroll
            for (int c = 0; c < 21; c++) a1[c] += p1 * vj[c];
        }
        float inv0 = 1.0f / l0, inv1 = 1.0f / l1;
        size_t base0 = (((size_t)b * 240 + i0) * 240 + h) * 21;
        size_t base1 = (((size_t)b * 240 + i1) * 240 + h) * 21;
        #pragma unroll
        for (int c = 0; c < 21; c++) { v1ws[base0 + c] = a0[c] * inv0; v1ws[base1 + c] = a1[c] * inv1; }
    }
}

// K3: axial stage 2 (tokens along h, per (b,w) column). grid = 1920, 128 thr.
__global__ __launch_bounds__(128) void k_ax2(const float* __restrict__ qws,
                                             const float* __restrict__ v1ws,
                                             float* __restrict__ y) {
    int b = blockIdx.x / 240;
    int w = blockIdx.x - b * 240;
    int tid = threadIdx.x;
    __shared__ float qs[240][24];
    __shared__ float vs[240][24];
    size_t base = ((size_t)b * 240 + w) * (240 * 21);
    for (int idx = tid; idx < 5040; idx += 128) {
        int i = idx / 21, c = idx - i * 21;
        qs[i][c] = qws[base + idx];
        vs[i][c] = v1ws[base + idx];
    }
    __syncthreads();

    if (tid < 120) {
        int i0 = tid, i1 = tid + 120;
        float qa[21], qbr[21];
        #pragma unroll
        for (int c = 0; c < 21; c++) { qa[c] = qs[i0][c]; qbr[c] = qs[i1][c]; }
        float m0 = -1e30f, l0 = 0.f, m1 = -1e30f, l1 = 0.f;
        float a0[21], a1[21];
        #pragma unroll
        for (int c = 0; c < 21; c++) { a0[c] = 0.f; a1[c] = 0.f; }
        for (int j = 0; j < 240; j++) {
            float qj[21], vj[21];
            #pragma unroll
            for (int c = 0; c < 21; c++) { qj[c] = qs[j][c]; vj[c] = vs[j][c]; }
            float s0 = 0.f, s1 = 0.f;
            #pragma unroll
            for (int c = 0; c < 21; c++) { s0 += qa[c] * qj[c]; s1 += qbr[c] * qj[c]; }
            if (s0 > m0) {
                float sc = __expf(m0 - s0); l0 *= sc;
                #pragma unroll
                for (int c = 0; c < 21; c++) a0[c] *= sc;
                m0 = s0;
            }
            float p0 = __expf(s0 - m0); l0 += p0;
            #pragma unroll
            for (int c = 0; c < 21; c++) a0[c] += p0 * vj[c];
            if (s1 > m1) {
                float sc = __expf(m1 - s1); l1 *= sc;
                #pragma unroll
                for (int c = 0; c < 21; c++) a1[c] *= sc;
                m1 = s1;
            }
            float p1 = __expf(s1 - m1); l1 += p1;
            #pragma unroll
            for (int c = 0; c < 21; c++) a1[c] += p1 * vj[c];
        }
        float inv0 = 1.0f / l0, inv1 = 1.0f / l1;
        #pragma unroll
        for (int c = 0; c < 21; c++) {
            y[((size_t)b * HWSZ + i0 * 240 + w) * 64 + 42 + c] = a0[c] * inv0;
            y[((size_t)b * HWSZ + i1 * 240 + w) * 64 + 42 + c] = a1[c] * inv1;
        }
    }
}

// K4: conv_out. thread per pixel, pixel-major y reads, SGPR weights, coalesced stores.
__global__ __launch_bounds__(256) void k_out(const float* __restrict__ y,
                                             const float* __restrict__ w_out,
                                             const float* __restrict__ b_out,
                                             float* __restrict__ out) {
    int p = blockIdx.x * 256 + threadIdx.x;
    if (p >= NPIX) return;
    int b = p / HWSZ;
    int hw = p - b * HWSZ;
    float yr[63];
    const float* yp = &y[(size_t)p * 64];
    #pragma unroll
    for (int c = 0; c < 63; c++) yr[c] = yp[c];
    #pragma unroll 1
    for (int o = 0; o < 63; o++) {
        float acc = b_out[o];
        const float* wr = &w_out[o * 63];
        #pragma unroll
        for (int c = 0; c < 63; c++) acc += wr[c] * yr[c];
        out[((size_t)(b * 63 + o)) * HWSZ + hw] = acc;
    }
}

extern "C" void kernel_launch(void* const* d_in, const int* in_sizes, int n_in,
                              void* d_out, int out_size, void* d_ws, size_t ws_size,
                              hipStream_t stream) {
    const float* x     = (const float*)d_in[0];
    const float* w_in  = (const float*)d_in[1];
    const float* b_in  = (const float*)d_in[2];
    const float* gamma = (const float*)d_in[3];
    const float* beta  = (const float*)d_in[4];
    const float* mean  = (const float*)d_in[5];
    const float* var   = (const float*)d_in[6];
    const float* w_out = (const float*)d_in[7];
    const float* b_out = (const float*)d_in[8];
    float* out = (float*)d_out;

    char* ws = (char*)d_ws;
    float* Weff = (float*)ws;                 // 7938 f32
    float* beff = Weff + 7938;                // 126 f32
    float* qws  = (float*)(ws + 32768);       // 8*240*240*21 f32 = 38.7MB  [b][w][h][c]
    float* v1ws = qws + 9676800;              // 38.7MB                      [b][w][h][c]
    float* yb   = v1ws + 9676800;             // 8*57600*64 f32 = 118MB      [b][hw][64]

    k_prep<<<32, 256, 0, stream>>>(w_in, b_in, gamma, beta, mean, var, Weff, beff);
    k_win <<<36864, 64, 0, stream>>>(x, Weff, beff, yb);
    k_ax1 <<<1920, 128, 0, stream>>>(x, Weff, beff, qws, v1ws);
    k_ax2 <<<1920, 128, 0, stream>>>(qws, v1ws, yb);
    k_out <<<1800, 256, 0, stream>>>(yb, w_out, b_out, out);
}

// Round 2
// 1376.637 us; speedup vs baseline: 1.4244x; 1.4244x over previous
//
#include <hip/hip_runtime.h>
#include <hip/hip_bf16.h>
#include <math.h>

#define CIN   63
#define HWSZ  57600
#define NPIX  460800   // 8*57600

// -------- K0: fold BN into conv_in weights --------
__global__ void k_prep(const float* __restrict__ w_in, const float* __restrict__ b_in,
                       const float* __restrict__ gamma, const float* __restrict__ beta,
                       const float* __restrict__ mean,  const float* __restrict__ var,
                       float* __restrict__ Weff, float* __restrict__ beff) {
    int idx = blockIdx.x * 256 + threadIdx.x;
    if (idx < 7938) {
        int o = idx / 63;
        float s = gamma[o] * rsqrtf(var[o] + 1e-5f);
        Weff[idx] = w_in[idx] * s;
    } else if (idx < 8064) {
        int o = idx - 7938;
        float s = gamma[o] * rsqrtf(var[o] + 1e-5f);
        beff[o] = b_in[o] * s + beta[o] - mean[o] * s;
    }
}

// -------- K1: window attention, 4 windows per 256-thread block (1 per wave) --------
// grid = 2 branches * 8 b * 48 wi * 12 col-groups = 9216
__global__ __launch_bounds__(256) void k_win(const float* __restrict__ x,
                                             const float* __restrict__ Weff,
                                             const float* __restrict__ beff,
                                             float* __restrict__ y) {
    int bid = blockIdx.x;
    int branch = bid / 4608;
    int r   = bid - branch * 4608;
    int b   = r / 576;
    int r2  = r - b * 576;
    int wi  = r2 / 12;
    int g   = r2 - wi * 12;          // column group: windows 4g..4g+3 -> cols 20g..20g+19
    int tid = threadIdx.x;
    int wv  = tid >> 6;              // wave -> window within group
    int lane = tid & 63;
    int qb  = branch * 42;
    int ish = branch ? 3 : 0;        // input roll  (-3,-3)
    int osh = branch ? 2 : 0;        // output roll (+2,+2)

    __shared__ float qv[4][25][43];      // 17.2KB (odd stride 43: conflict-free)
    __shared__ float Wl[42 * 63];        // 10.6KB
    __shared__ float xin_s[100 * 65];    // 26KB; S[4][25][27] aliased here after projection
    float (*xin)[65] = (float(*)[65])xin_s;
    float (*S)[25][27] = (float(*)[25][27])xin_s;

    // stage W slice (linear, coalesced, conflict-free)
    for (int idx = tid; idx < 2646; idx += 256) Wl[idx] = Weff[qb * 63 + idx];
    // stage x: 100 pixels (5 rows x 20 cols) x 63 ch ; 80B-contiguous global runs
    for (int idx = tid; idx < 6300; idx += 256) {
        int ch = idx / 100, p = idx - ch * 100;
        int pr = p / 20, pc = p - pr * 20;
        int ih = (wi * 5 + pr + ish) % 240;
        int iw = (g * 20 + pc + ish) % 240;
        xin[p][ch] = x[((size_t)(b * 63 + ch)) * HWSZ + ih * 240 + iw];
    }
    __syncthreads();

    // projection: each lane computes one (q,v) pair; W from LDS, xin broadcast
    for (int idx = lane; idx < 525; idx += 64) {
        int pw = idx / 21, o = idx - pw * 21;
        int pr = pw / 5, pc = pw - pr * 5;
        int sp = pr * 20 + wv * 5 + pc;
        float aq = beff[qb + o], av = beff[qb + 21 + o];
        const float* wq = &Wl[o * 63];
        const float* wv_ = &Wl[(o + 21) * 63];
        #pragma unroll
        for (int ch = 0; ch < 63; ch++) {
            float xv = xin[sp][ch];
            aq += wq[ch] * xv;
            av += wv_[ch] * xv;
        }
        qv[wv][pw][o] = aq;
        qv[wv][pw][21 + o] = av;
    }
    __syncthreads();   // all waves done with xin -> safe to write S (aliased)

    // scores S = q q^T (25x25) per wave
    for (int idx = lane; idx < 625; idx += 64) {
        int i = idx / 25, j = idx - i * 25;
        float s = 0.f;
        #pragma unroll
        for (int c = 0; c < 21; c++) s += qv[wv][i][c] * qv[wv][j][c];
        S[wv][i][j] = s;
    }
    __syncthreads();

    // softmax rows
    if (lane < 25) {
        float m = -1e30f;
        #pragma unroll
        for (int j = 0; j < 25; j++) m = fmaxf(m, S[wv][lane][j]);
        float sum = 0.f;
        #pragma unroll
        for (int j = 0; j < 25; j++) { float e = __expf(S[wv][lane][j] - m); sum += e; S[wv][lane][j] = e; }
        float inv = 1.0f / sum;
        #pragma unroll
        for (int j = 0; j < 25; j++) S[wv][lane][j] *= inv;
    }
    __syncthreads();

    // out = P @ v
    for (int idx = lane; idx < 525; idx += 64) {
        int pw = idx / 21, o = idx - pw * 21;
        float acc = 0.f;
        #pragma unroll
        for (int j = 0; j < 25; j++) acc += S[wv][pw][j] * qv[wv][j][21 + o];
        int pr = pw / 5, pc = pw - pr * 5;
        int oh = (wi * 5 + pr + osh) % 240;
        int ow = (g * 20 + wv * 5 + pc + osh) % 240;
        y[((size_t)b * HWSZ + oh * 240 + ow) * 64 + branch * 21 + o] = acc;
    }
}

// -------- K2: axial stage 1 (tokens along w). grid = 1920, 256 thr, 1 row/thread --------
__global__ __launch_bounds__(256) void k_ax1(const float* __restrict__ x,
                                             const float* __restrict__ Weff,
                                             const float* __restrict__ beff,
                                             float* __restrict__ qws,
                                             float* __restrict__ v1ws) {
    int b = blockIdx.x / 240;
    int h = blockIdx.x - b * 240;
    int tid = threadIdx.x;
    __shared__ float qs[240][21];    // stride 21 (odd): conflict-free
    __shared__ float vs[240][21];

    if (tid < 240) {
        float xr[63];
        #pragma unroll
        for (int ch = 0; ch < 63; ch++)
            xr[ch] = x[((size_t)(b * 63 + ch)) * HWSZ + h * 240 + tid];
        #pragma unroll 1
        for (int o = 0; o < 21; o++) {
            float aq = beff[84 + o], av = beff[105 + o];
            const float* wq = &Weff[(84 + o) * 63];
            const float* wv_ = &Weff[(105 + o) * 63];
            #pragma unroll
            for (int ch = 0; ch < 63; ch++) {
                aq += wq[ch] * xr[ch];   // uniform addr -> scalar loads
                av += wv_[ch] * xr[ch];
            }
            qs[tid][o] = aq;
            vs[tid][o] = av;
        }
    }
    __syncthreads();

    // persist q^T ([b][w][h][c]) for stage 2
    for (int idx = tid; idx < 5040; idx += 256) {
        int i = idx / 21, c = idx - i * 21;
        qws[(((size_t)b * 240 + i) * 240 + h) * 21 + c] = qs[i][c];
    }

    if (tid < 240) {
        float q0[21], a0[21];
        #pragma unroll
        for (int c = 0; c < 21; c++) { q0[c] = qs[tid][c]; a0[c] = 0.f; }
        float m0 = -1e30f, l0 = 0.f;
        for (int j = 0; j < 240; j++) {
            float s = 0.f;
            #pragma unroll
            for (int c = 0; c < 21; c++) s += q0[c] * qs[j][c];
            if (s > m0) {
                float sc = __expf(m0 - s); l0 *= sc;
                #pragma unroll
                for (int c = 0; c < 21; c++) a0[c] *= sc;
                m0 = s;
            }
            float p = __expf(s - m0); l0 += p;
            #pragma unroll
            for (int c = 0; c < 21; c++) a0[c] += p * vs[j][c];
        }
        float inv = 1.0f / l0;
        size_t base = (((size_t)b * 240 + tid) * 240 + h) * 21;
        #pragma unroll
        for (int c = 0; c < 21; c++) v1ws[base + c] = a0[c] * inv;
    }
}

// -------- K3: axial stage 2 (tokens along h). grid = 1920, 256 thr --------
__global__ __launch_bounds__(256) void k_ax2(const float* __restrict__ qws,
                                             const float* __restrict__ v1ws,
                                             float* __restrict__ y) {
    int b = blockIdx.x / 240;
    int w = blockIdx.x - b * 240;
    int tid = threadIdx.x;
    __shared__ float qs[240][21];
    __shared__ float vs[240][21];
    size_t base = ((size_t)b * 240 + w) * 5040;
    for (int idx = tid; idx < 5040; idx += 256) {
        ((float*)qs)[idx] = qws[base + idx];
        ((float*)vs)[idx] = v1ws[base + idx];
    }
    __syncthreads();

    if (tid < 240) {
        float q0[21], a0[21];
        #pragma unroll
        for (int c = 0; c < 21; c++) { q0[c] = qs[tid][c]; a0[c] = 0.f; }
        float m0 = -1e30f, l0 = 0.f;
        for (int j = 0; j < 240; j++) {
            float s = 0.f;
            #pragma unroll
            for (int c = 0; c < 21; c++) s += q0[c] * qs[j][c];
            if (s > m0) {
                float sc = __expf(m0 - s); l0 *= sc;
                #pragma unroll
                for (int c = 0; c < 21; c++) a0[c] *= sc;
                m0 = s;
            }
            float p = __expf(s - m0); l0 += p;
            #pragma unroll
            for (int c = 0; c < 21; c++) a0[c] += p * vs[j][c];
        }
        float inv = 1.0f / l0;
        #pragma unroll
        for (int c = 0; c < 21; c++)
            y[((size_t)b * HWSZ + tid * 240 + w) * 64 + 42 + c] = a0[c] * inv;
    }
}

// -------- K4: conv_out --------
__global__ __launch_bounds__(256) void k_out(const float* __restrict__ y,
                                             const float* __restrict__ w_out,
                                             const float* __restrict__ b_out,
                                             float* __restrict__ out) {
    int p = blockIdx.x * 256 + threadIdx.x;
    if (p >= NPIX) return;
    int b = p / HWSZ;
    int hw = p - b * HWSZ;
    float yr[63];
    const float* yp = &y[(size_t)p * 64];
    #pragma unroll
    for (int c = 0; c < 63; c++) yr[c] = yp[c];
    #pragma unroll 1
    for (int o = 0; o < 63; o++) {
        float acc = b_out[o];
        const float* wr = &w_out[o * 63];
        #pragma unroll
        for (int c = 0; c < 63; c++) acc += wr[c] * yr[c];
        out[((size_t)(b * 63 + o)) * HWSZ + hw] = acc;
    }
}

extern "C" void kernel_launch(void* const* d_in, const int* in_sizes, int n_in,
                              void* d_out, int out_size, void* d_ws, size_t ws_size,
                              hipStream_t stream) {
    const float* x     = (const float*)d_in[0];
    const float* w_in  = (const float*)d_in[1];
    const float* b_in  = (const float*)d_in[2];
    const float* gamma = (const float*)d_in[3];
    const float* beta  = (const float*)d_in[4];
    const float* mean  = (const float*)d_in[5];
    const float* var   = (const float*)d_in[6];
    const float* w_out = (const float*)d_in[7];
    const float* b_out = (const float*)d_in[8];
    float* out = (float*)d_out;

    char* ws = (char*)d_ws;
    float* Weff = (float*)ws;                 // 7938 f32
    float* beff = Weff + 7938;                // 126 f32
    float* qws  = (float*)(ws + 32768);       // 38.7MB  [b][w][h][21]
    float* v1ws = qws + 9676800;              // 38.7MB  [b][w][h][21]
    float* yb   = v1ws + 9676800;             // 118MB   [b][hw][64]

    k_prep<<<32, 256, 0, stream>>>(w_in, b_in, gamma, beta, mean, var, Weff, beff);
    k_win <<<9216, 256, 0, stream>>>(x, Weff, beff, yb);
    k_ax1 <<<1920, 256, 0, stream>>>(x, Weff, beff, qws, v1ws);
    k_ax2 <<<1920, 256, 0, stream>>>(qws, v1ws, yb);
    k_out <<<1800, 256, 0, stream>>>(yb, w_out, b_out, out);
}

// Round 4
// 677.842 us; speedup vs baseline: 2.8928x; 2.0309x over previous
//
#include <hip/hip_runtime.h>
#include <math.h>

#define HWSZ  57600
#define NPIX  460800   // 8*57600

typedef __attribute__((ext_vector_type(8))) short bf16x8;
typedef __attribute__((ext_vector_type(4))) float f32x4;

__device__ __forceinline__ unsigned short f2b(float f) {
    unsigned int u = __float_as_uint(f);
    unsigned int r = (u + 0x7FFFu + ((u >> 16) & 1u)) >> 16;
    return (unsigned short)r;
}
__device__ __forceinline__ float b2f(unsigned short s) {
    return __uint_as_float(((unsigned int)s) << 16);
}

// -------- K0: fold BN into conv_in weights --------
__global__ void k_prep(const float* __restrict__ w_in, const float* __restrict__ b_in,
                       const float* __restrict__ gamma, const float* __restrict__ beta,
                       const float* __restrict__ mean,  const float* __restrict__ var,
                       float* __restrict__ Weff, float* __restrict__ beff) {
    int idx = blockIdx.x * 256 + threadIdx.x;
    if (idx < 7938) {
        int o = idx / 63;
        float s = gamma[o] * rsqrtf(var[o] + 1e-5f);
        Weff[idx] = w_in[idx] * s;
    } else if (idx < 8064) {
        int o = idx - 7938;
        float s = gamma[o] * rsqrtf(var[o] + 1e-5f);
        beff[o] = b_in[o] * s + beta[o] - mean[o] * s;
    }
}

// -------- K_proj: full 126-ch projection, thread per pixel, bf16 channel-major out --------
__global__ __launch_bounds__(256) void k_proj(const float* __restrict__ x,
                                              const float* __restrict__ Weff,
                                              const float* __restrict__ beff,
                                              unsigned short* __restrict__ xp) {
    int p = blockIdx.x * 256 + threadIdx.x;
    if (p >= NPIX) return;
    int b = p / HWSZ;
    int hw = p - b * HWSZ;
    float xr[63];
    const float* xb = x + (size_t)b * 63 * HWSZ + hw;
    #pragma unroll
    for (int c = 0; c < 63; c++) xr[c] = xb[(size_t)c * HWSZ];
    #pragma unroll 1
    for (int o = 0; o < 126; o++) {
        float acc = beff[o];
        const float* wr = &Weff[o * 63];
        #pragma unroll
        for (int c = 0; c < 63; c++) acc += wr[c] * xr[c];
        xp[(size_t)o * NPIX + p] = f2b(acc);
    }
}

// -------- K1: window attention (attention only; q,v from xp) --------
// grid = 2 branches * 8 b * 48 wi * 12 col-groups = 9216
__global__ __launch_bounds__(256) void k_win(const unsigned short* __restrict__ xp,
                                             unsigned short* __restrict__ ybA) {
    int bid = blockIdx.x;
    int branch = bid / 4608;
    int r   = bid - branch * 4608;
    int b   = r / 576;
    int r2  = r - b * 576;
    int wi  = r2 / 12;
    int g   = r2 - wi * 12;
    int tid = threadIdx.x;
    int wv  = tid >> 6;
    int lane = tid & 63;
    int ish = branch ? 3 : 0;
    int osh = branch ? 2 : 0;

    __shared__ float qv[4][25][43];
    __shared__ float S[4][25][27];

    // stage q,v from xp (bf16, channel-major): 42 ch x 100 px
    for (int idx = tid; idx < 4200; idx += 256) {
        int ch = idx / 100, p100 = idx - ch * 100;
        int pr = p100 / 20, pc20 = p100 - pr * 20;
        int ih = (wi * 5 + pr + ish) % 240;
        int iw = (g * 20 + pc20 + ish) % 240;
        float v = b2f(xp[(size_t)(branch * 42 + ch) * NPIX + (size_t)b * HWSZ + ih * 240 + iw]);
        qv[pc20 / 5][pr * 5 + (pc20 % 5)][ch] = v;
    }
    __syncthreads();

    // scores S = q q^T (25x25) per wave
    for (int idx = lane; idx < 625; idx += 64) {
        int i = idx / 25, j = idx - i * 25;
        float s = 0.f;
        #pragma unroll
        for (int c = 0; c < 21; c++) s += qv[wv][i][c] * qv[wv][j][c];
        S[wv][i][j] = s;
    }
    __syncthreads();

    if (lane < 25) {
        float m = -1e30f;
        #pragma unroll
        for (int j = 0; j < 25; j++) m = fmaxf(m, S[wv][lane][j]);
        float sum = 0.f;
        #pragma unroll
        for (int j = 0; j < 25; j++) { float e = __expf(S[wv][lane][j] - m); sum += e; S[wv][lane][j] = e; }
        float inv = 1.0f / sum;
        #pragma unroll
        for (int j = 0; j < 25; j++) S[wv][lane][j] *= inv;
    }
    __syncthreads();

    for (int idx = lane; idx < 525; idx += 64) {
        int pw = idx / 21, o = idx - pw * 21;
        float acc = 0.f;
        #pragma unroll
        for (int j = 0; j < 25; j++) acc += S[wv][pw][j] * qv[wv][j][21 + o];
        int pr = pw / 5, pc = pw - pr * 5;
        int oh = (wi * 5 + pr + osh) % 240;
        int ow = (g * 20 + wv * 5 + pc + osh) % 240;
        ybA[((size_t)b * HWSZ + oh * 240 + ow) * 42 + branch * 21 + o] = f2b(acc);
    }
}

// -------- MFMA axial attention core: 240 tokens, 21 ch, block = 4 waves --------
// Q: [240][40] bf16 token-major (k=21..31 zero); Vt: [32][264] bf16 ch-major (pads zero)
// Pl: [64][136] bf16 (per-wave-private 16-row stripes)
// 15 row-tiles of 16: wave wv handles tiles {mt*4+wv}; tile 15 (rows 240..255) skipped.
__device__ __forceinline__ void axial_core(const unsigned short* Q, const unsigned short* Vt,
                                           unsigned short* Pl,
                                           unsigned short* outp, size_t obase) {
    int tid = threadIdx.x;
    int wv = tid >> 6, l = tid & 63;
    int lr = l & 15, lq = l >> 4;
    const f32x4 zf = {0.f, 0.f, 0.f, 0.f};
    int m0 = wv * 16;

    for (int mt = 0; mt < 4; mt++) {
        if (mt == 3 && wv == 3) continue;   // tile 15 would be rows 240..255 (OOB)
        int rbase = mt * 64 + wv * 16;
        bf16x8 afr = *(const bf16x8*)&Q[(rbase + lr) * 40 + lq * 8];
        f32x4 d[15];
        #pragma unroll
        for (int jt = 0; jt < 15; jt++) {
            bf16x8 bfr = *(const bf16x8*)&Q[(jt * 16 + lr) * 40 + lq * 8];
            d[jt] = __builtin_amdgcn_mfma_f32_16x16x32_bf16(afr, bfr, zf, 0, 0, 0);
        }
        float mx[4] = {-1e30f, -1e30f, -1e30f, -1e30f};
        #pragma unroll
        for (int jt = 0; jt < 15; jt++)
            #pragma unroll
            for (int r = 0; r < 4; r++) mx[r] = fmaxf(mx[r], d[jt][r]);
        #pragma unroll
        for (int s = 1; s < 16; s <<= 1)
            #pragma unroll
            for (int r = 0; r < 4; r++) mx[r] = fmaxf(mx[r], __shfl_xor(mx[r], s));
        float sm[4] = {0.f, 0.f, 0.f, 0.f};
        #pragma unroll
        for (int jt = 0; jt < 15; jt++)
            #pragma unroll
            for (int r = 0; r < 4; r++) { float e = __expf(d[jt][r] - mx[r]); d[jt][r] = e; sm[r] += e; }
        #pragma unroll
        for (int s = 1; s < 16; s <<= 1)
            #pragma unroll
            for (int r = 0; r < 4; r++) sm[r] += __shfl_xor(sm[r], s);
        float inv[4];
        #pragma unroll
        for (int r = 0; r < 4; r++) inv[r] = 1.0f / sm[r];

        // P half 0: token-cols 0..127 (tiles 0..7)  [Pl rows are wave-private]
        #pragma unroll
        for (int jt = 0; jt < 8; jt++)
            #pragma unroll
            for (int r = 0; r < 4; r++)
                Pl[(m0 + lq * 4 + r) * 136 + jt * 16 + lr] = f2b(d[jt][r] * inv[r]);
        f32x4 y0 = zf, y1 = zf;
        #pragma unroll
        for (int ks = 0; ks < 4; ks++) {
            bf16x8 pa = *(const bf16x8*)&Pl[(m0 + lr) * 136 + ks * 32 + lq * 8];
            bf16x8 v0 = *(const bf16x8*)&Vt[lr * 264 + ks * 32 + lq * 8];
            bf16x8 v1f = *(const bf16x8*)&Vt[(lr + 16) * 264 + ks * 32 + lq * 8];
            y0 = __builtin_amdgcn_mfma_f32_16x16x32_bf16(pa, v0, y0, 0, 0, 0);
            y1 = __builtin_amdgcn_mfma_f32_16x16x32_bf16(pa, v1f, y1, 0, 0, 0);
        }
        // P half 1: token-cols 128..239 + zeros 240..255
        #pragma unroll
        for (int jt = 8; jt < 15; jt++)
            #pragma unroll
            for (int r = 0; r < 4; r++)
                Pl[(m0 + lq * 4 + r) * 136 + (jt - 8) * 16 + lr] = f2b(d[jt][r] * inv[r]);
        #pragma unroll
        for (int r = 0; r < 4; r++)
            Pl[(m0 + lq * 4 + r) * 136 + 112 + lr] = 0;
        #pragma unroll
        for (int ks = 0; ks < 4; ks++) {
            bf16x8 pa = *(const bf16x8*)&Pl[(m0 + lr) * 136 + ks * 32 + lq * 8];
            bf16x8 v0 = *(const bf16x8*)&Vt[lr * 264 + (ks + 4) * 32 + lq * 8];
            bf16x8 v1f = *(const bf16x8*)&Vt[(lr + 16) * 264 + (ks + 4) * 32 + lq * 8];
            y0 = __builtin_amdgcn_mfma_f32_16x16x32_bf16(pa, v0, y0, 0, 0, 0);
            y1 = __builtin_amdgcn_mfma_f32_16x16x32_bf16(pa, v1f, y1, 0, 0, 0);
        }
        // store Y: row = 4*lq + r within tile, col = lr (+16)
        #pragma unroll
        for (int r = 0; r < 4; r++) {
            int tok = rbase + lq * 4 + r;
            size_t oa = obase + (size_t)tok * 5040;
            outp[oa + lr] = f2b(y0[r]);
            if (lr < 5) outp[oa + 16 + lr] = f2b(y1[r]);
        }
    }
}

// -------- K2: axial stage 1 (tokens along w). grid = 1920 --------
__global__ __launch_bounds__(256) void k_ax1(const unsigned short* __restrict__ xp,
                                             unsigned short* __restrict__ qt,
                                             unsigned short* __restrict__ v1) {
    __shared__ __align__(16) unsigned short Q[240 * 40];
    __shared__ __align__(16) unsigned short Vt[32 * 264];
    __shared__ __align__(16) unsigned short Pl[64 * 136];
    int b = blockIdx.x / 240, h = blockIdx.x % 240;
    int tid = threadIdx.x;
    for (int i = tid; i < 4800; i += 256) ((unsigned int*)Q)[i] = 0;
    for (int i = tid; i < 4224; i += 256) ((unsigned int*)Vt)[i] = 0;
    __syncthreads();
    size_t xb = (size_t)b * HWSZ + h * 240;
    for (int idx = tid; idx < 5040; idx += 256) {
        int c = idx / 240, w = idx - c * 240;
        Q[w * 40 + c]   = xp[(size_t)(84 + c) * NPIX + xb + w];
        Vt[c * 264 + w] = xp[(size_t)(105 + c) * NPIX + xb + w];
    }
    __syncthreads();
    // persist q token-major for stage 2: qt[b][w][h][c]
    size_t qtb = (size_t)b * 1209600 + h * 21;
    for (int idx = tid; idx < 5040; idx += 256) {
        int w = idx / 21, c = idx - w * 21;
        qt[qtb + (size_t)w * 5040 + c] = Q[w * 40 + c];
    }
    axial_core(Q, Vt, Pl, v1, (size_t)b * 1209600 + h * 21);
}

// -------- K3: axial stage 2 (tokens along h). grid = 1920 --------
__global__ __launch_bounds__(256) void k_ax2(const unsigned short* __restrict__ qt,
                                             const unsigned short* __restrict__ v1,
                                             unsigned short* __restrict__ ybB) {
    __shared__ __align__(16) unsigned short Q[240 * 40];
    __shared__ __align__(16) unsigned short Vt[32 * 264];
    __shared__ __align__(16) unsigned short Pl[64 * 136];
    int b = blockIdx.x / 240, w = blockIdx.x % 240;
    int tid = threadIdx.x;
    for (int i = tid; i < 4800; i += 256) ((unsigned int*)Q)[i] = 0;
    for (int i = tid; i < 4224; i += 256) ((unsigned int*)Vt)[i] = 0;
    __syncthreads();
    size_t base = ((size_t)b * 240 + w) * 5040;
    for (int idx = tid; idx < 5040; idx += 256) {
        int h = idx / 21, c = idx - h * 21;
        Q[h * 40 + c]   = qt[base + idx];
        Vt[c * 264 + h] = v1[base + idx];
    }
    __syncthreads();
    axial_core(Q, Vt, Pl, ybB, (size_t)b * 1209600 + w * 21);
}

// -------- K4: conv_out --------
__global__ __launch_bounds__(256) void k_out(const unsigned short* __restrict__ ybA,
                                             const unsigned short* __restrict__ ybB,
                                             const float* __restrict__ w_out,
                                             const float* __restrict__ b_out,
                                             float* __restrict__ out) {
    int p = blockIdx.x * 256 + threadIdx.x;
    if (p >= NPIX) return;
    int b = p / HWSZ;
    int hw = p - b * HWSZ;
    float yr[63];
    const unsigned short* a = ybA + (size_t)p * 42;
    #pragma unroll
    for (int c = 0; c < 42; c++) yr[c] = b2f(a[c]);
    const unsigned short* bb = ybB + (size_t)p * 21;
    #pragma unroll
    for (int c = 0; c < 21; c++) yr[42 + c] = b2f(bb[c]);
    #pragma unroll 1
    for (int o = 0; o < 63; o++) {
        float acc = b_out[o];
        const float* wr = &w_out[o * 63];
        #pragma unroll
        for (int c = 0; c < 63; c++) acc += wr[c] * yr[c];
        out[((size_t)(b * 63 + o)) * HWSZ + hw] = acc;
    }
}

extern "C" void kernel_launch(void* const* d_in, const int* in_sizes, int n_in,
                              void* d_out, int out_size, void* d_ws, size_t ws_size,
                              hipStream_t stream) {
    const float* x     = (const float*)d_in[0];
    const float* w_in  = (const float*)d_in[1];
    const float* b_in  = (const float*)d_in[2];
    const float* gamma = (const float*)d_in[3];
    const float* beta  = (const float*)d_in[4];
    const float* mean  = (const float*)d_in[5];
    const float* var   = (const float*)d_in[6];
    const float* w_out = (const float*)d_in[7];
    const float* b_out = (const float*)d_in[8];
    float* out = (float*)d_out;

    char* ws = (char*)d_ws;
    // xp bf16 [126][NPIX]  : [0, 116,121,600)
    // ybA bf16 [NPIX][42]  : [116121600, 154828800)
    // Weff/beff            : [154828800, ...)
    // qt / v1 / ybB alias xp channels 0..62 region (dead after k_win):
    unsigned short* xp  = (unsigned short*)ws;
    unsigned short* ybA = (unsigned short*)(ws + 116121600);
    float* Weff = (float*)(ws + 154828800);
    float* beff = (float*)(ws + 154861568);
    unsigned short* qt  = (unsigned short*)ws;
    unsigned short* v1  = (unsigned short*)(ws + 19353600);
    unsigned short* ybB = (unsigned short*)(ws + 38707200);

    k_prep<<<32, 256, 0, stream>>>(w_in, b_in, gamma, beta, mean, var, Weff, beff);
    k_proj<<<1800, 256, 0, stream>>>(x, Weff, beff, xp);
    k_win <<<9216, 256, 0, stream>>>(xp, ybA);
    k_ax1 <<<1920, 256, 0, stream>>>(xp, qt, v1);
    k_ax2 <<<1920, 256, 0, stream>>>(qt, v1, ybB);
    k_out <<<1800, 256, 0, stream>>>(ybA, ybB, w_out, b_out, out);
}

// Round 5
// 469.258 us; speedup vs baseline: 4.1787x; 1.4445x over previous
//
#include <hip/hip_runtime.h>
#include <math.h>

#define HWSZ  57600
#define NPIX  460800   // 8*57600

typedef __attribute__((ext_vector_type(8))) short bf16x8;
typedef __attribute__((ext_vector_type(4))) float f32x4;

__device__ __forceinline__ unsigned short f2b(float f) {
    unsigned int u = __float_as_uint(f);
    unsigned int r = (u + 0x7FFFu + ((u >> 16) & 1u)) >> 16;
    return (unsigned short)r;
}
__device__ __forceinline__ float b2f(unsigned short s) {
    return __uint_as_float(((unsigned int)s) << 16);
}

// -------- K0: fold BN into conv_in weights --------
__global__ void k_prep(const float* __restrict__ w_in, const float* __restrict__ b_in,
                       const float* __restrict__ gamma, const float* __restrict__ beta,
                       const float* __restrict__ mean,  const float* __restrict__ var,
                       float* __restrict__ Weff, float* __restrict__ beff) {
    int idx = blockIdx.x * 256 + threadIdx.x;
    if (idx < 7938) {
        int o = idx / 63;
        float s = gamma[o] * rsqrtf(var[o] + 1e-5f);
        Weff[idx] = w_in[idx] * s;
    } else if (idx < 8064) {
        int o = idx - 7938;
        float s = gamma[o] * rsqrtf(var[o] + 1e-5f);
        beff[o] = b_in[o] * s + beta[o] - mean[o] * s;
    }
}

// -------- K_proj (MFMA): xp[o][p] = sum_c Weff[o][c] * x[c][p] + beff[o] --------
// block = 256 px, grid = 1800 (225 blocks per batch; HWSZ%256==0 so no batch straddle)
#define XS 66
#define WSTR 66
__global__ __launch_bounds__(256) void k_projM(const float* __restrict__ x,
                                               const float* __restrict__ Weff,
                                               const float* __restrict__ beff,
                                               unsigned short* __restrict__ xp) {
    __shared__ __align__(16) unsigned short Xl[256 * XS];   // [pixel][k] bf16, k=63 zero
    __shared__ __align__(16) unsigned short Wl[128 * WSTR]; // [o][k] bf16, o>=126 & k=63 zero
    __shared__ float bl[128];
    int blk = blockIdx.x;
    int tid = threadIdx.x;
    int b = blk / 225;
    int hw0 = (blk - b * 225) * 256;
    int wv = tid >> 6, l = tid & 63;
    int lr = l & 15, lq = l >> 4;
    const f32x4 zf = {0.f, 0.f, 0.f, 0.f};

    // stage x tile: 63 channels, packed 2-at-a-time (c=62 pairs with zero pad)
    {
        const float* xb = x + (size_t)b * 63 * HWSZ + hw0 + tid;
        unsigned short* xr = &Xl[tid * XS];
        #pragma unroll
        for (int c = 0; c < 62; c += 2) {
            unsigned int lo = f2b(xb[(size_t)c * HWSZ]);
            unsigned int hi = f2b(xb[(size_t)(c + 1) * HWSZ]);
            *(unsigned int*)&xr[c] = lo | (hi << 16);
        }
        unsigned int lo = f2b(xb[(size_t)62 * HWSZ]);
        *(unsigned int*)&xr[62] = lo;   // k=63 zeroed
    }
    // stage W + zero pads
    for (int idx = tid; idx < 7938; idx += 256) {
        int o = idx / 63, c = idx - o * 63;
        Wl[o * WSTR + c] = f2b(Weff[idx]);
    }
    for (int idx = tid; idx < 128; idx += 256) {
        Wl[idx * WSTR + 63] = 0;
        bl[idx] = (idx < 126) ? beff[idx] : 0.f;
    }
    for (int idx = tid; idx < 128; idx += 256) Wl[(126 + (idx >> 6)) * WSTR + (idx & 63)] = 0;
    __syncthreads();

    // A-frags (W) loaded once, reused for all pixel tiles
    bf16x8 wa[8][2];
    #pragma unroll
    for (int ot = 0; ot < 8; ot++)
        #pragma unroll
        for (int ks = 0; ks < 2; ks++)
            wa[ot][ks] = *(const bf16x8*)&Wl[(ot * 16 + lr) * WSTR + ks * 32 + lq * 8];

    for (int pt = 0; pt < 4; pt++) {
        int prow = (wv * 4 + pt) * 16;
        bf16x8 xb0 = *(const bf16x8*)&Xl[(prow + lr) * XS + lq * 8];
        bf16x8 xb1 = *(const bf16x8*)&Xl[(prow + lr) * XS + 32 + lq * 8];
        f32x4 acc[8];
        #pragma unroll
        for (int ot = 0; ot < 8; ot++) {
            acc[ot] = __builtin_amdgcn_mfma_f32_16x16x32_bf16(wa[ot][0], xb0, zf, 0, 0, 0);
            acc[ot] = __builtin_amdgcn_mfma_f32_16x16x32_bf16(wa[ot][1], xb1, acc[ot], 0, 0, 0);
        }
        size_t pbase = (size_t)b * HWSZ + hw0 + prow + lr;
        #pragma unroll
        for (int ot = 0; ot < 8; ot++) {
            #pragma unroll
            for (int r = 0; r < 4; r++) {
                int o = ot * 16 + lq * 4 + r;
                if (o < 126)
                    xp[(size_t)o * NPIX + pbase] = f2b(acc[ot][r] + bl[o]);
            }
        }
    }
}

// -------- K1: window attention (attention only; q,v from xp) --------
// grid = 2 branches * 8 b * 48 wi * 12 col-groups = 9216
__global__ __launch_bounds__(256) void k_win(const unsigned short* __restrict__ xp,
                                             unsigned short* __restrict__ ybA) {
    int bid = blockIdx.x;
    int branch = bid / 4608;
    int r   = bid - branch * 4608;
    int b   = r / 576;
    int r2  = r - b * 576;
    int wi  = r2 / 12;
    int g   = r2 - wi * 12;
    int tid = threadIdx.x;
    int wv  = tid >> 6;
    int lane = tid & 63;
    int ish = branch ? 3 : 0;
    int osh = branch ? 2 : 0;

    __shared__ float qv[4][25][43];
    __shared__ float S[4][25][27];

    for (int idx = tid; idx < 4200; idx += 256) {
        int ch = idx / 100, p100 = idx - ch * 100;
        int pr = p100 / 20, pc20 = p100 - pr * 20;
        int ih = (wi * 5 + pr + ish) % 240;
        int iw = (g * 20 + pc20 + ish) % 240;
        float v = b2f(xp[(size_t)(branch * 42 + ch) * NPIX + (size_t)b * HWSZ + ih * 240 + iw]);
        qv[pc20 / 5][pr * 5 + (pc20 % 5)][ch] = v;
    }
    __syncthreads();

    for (int idx = lane; idx < 625; idx += 64) {
        int i = idx / 25, j = idx - i * 25;
        float s = 0.f;
        #pragma unroll
        for (int c = 0; c < 21; c++) s += qv[wv][i][c] * qv[wv][j][c];
        S[wv][i][j] = s;
    }
    __syncthreads();

    if (lane < 25) {
        float m = -1e30f;
        #pragma unroll
        for (int j = 0; j < 25; j++) m = fmaxf(m, S[wv][lane][j]);
        float sum = 0.f;
        #pragma unroll
        for (int j = 0; j < 25; j++) { float e = __expf(S[wv][lane][j] - m); sum += e; S[wv][lane][j] = e; }
        float inv = 1.0f / sum;
        #pragma unroll
        for (int j = 0; j < 25; j++) S[wv][lane][j] *= inv;
    }
    __syncthreads();

    for (int idx = lane; idx < 525; idx += 64) {
        int pw = idx / 21, o = idx - pw * 21;
        float acc = 0.f;
        #pragma unroll
        for (int j = 0; j < 25; j++) acc += S[wv][pw][j] * qv[wv][j][21 + o];
        int pr = pw / 5, pc = pw - pr * 5;
        int oh = (wi * 5 + pr + osh) % 240;
        int ow = (g * 20 + wv * 5 + pc + osh) % 240;
        ybA[((size_t)b * HWSZ + oh * 240 + ow) * 42 + branch * 21 + o] = f2b(acc);
    }
}

// -------- MFMA axial attention core (verified round 4) --------
__device__ __forceinline__ void axial_core(const unsigned short* Q, const unsigned short* Vt,
                                           unsigned short* Pl,
                                           unsigned short* outp, size_t obase) {
    int tid = threadIdx.x;
    int wv = tid >> 6, l = tid & 63;
    int lr = l & 15, lq = l >> 4;
    const f32x4 zf = {0.f, 0.f, 0.f, 0.f};
    int m0 = wv * 16;

    for (int mt = 0; mt < 4; mt++) {
        if (mt == 3 && wv == 3) continue;   // tile 15 would be rows 240..255 (OOB)
        int rbase = mt * 64 + wv * 16;
        bf16x8 afr = *(const bf16x8*)&Q[(rbase + lr) * 40 + lq * 8];
        f32x4 d[15];
        #pragma unroll
        for (int jt = 0; jt < 15; jt++) {
            bf16x8 bfr = *(const bf16x8*)&Q[(jt * 16 + lr) * 40 + lq * 8];
            d[jt] = __builtin_amdgcn_mfma_f32_16x16x32_bf16(afr, bfr, zf, 0, 0, 0);
        }
        float mx[4] = {-1e30f, -1e30f, -1e30f, -1e30f};
        #pragma unroll
        for (int jt = 0; jt < 15; jt++)
            #pragma unroll
            for (int r = 0; r < 4; r++) mx[r] = fmaxf(mx[r], d[jt][r]);
        #pragma unroll
        for (int s = 1; s < 16; s <<= 1)
            #pragma unroll
            for (int r = 0; r < 4; r++) mx[r] = fmaxf(mx[r], __shfl_xor(mx[r], s));
        float sm[4] = {0.f, 0.f, 0.f, 0.f};
        #pragma unroll
        for (int jt = 0; jt < 15; jt++)
            #pragma unroll
            for (int r = 0; r < 4; r++) { float e = __expf(d[jt][r] - mx[r]); d[jt][r] = e; sm[r] += e; }
        #pragma unroll
        for (int s = 1; s < 16; s <<= 1)
            #pragma unroll
            for (int r = 0; r < 4; r++) sm[r] += __shfl_xor(sm[r], s);
        float inv[4];
        #pragma unroll
        for (int r = 0; r < 4; r++) inv[r] = 1.0f / sm[r];

        #pragma unroll
        for (int jt = 0; jt < 8; jt++)
            #pragma unroll
            for (int r = 0; r < 4; r++)
                Pl[(m0 + lq * 4 + r) * 136 + jt * 16 + lr] = f2b(d[jt][r] * inv[r]);
        f32x4 y0 = zf, y1 = zf;
        #pragma unroll
        for (int ks = 0; ks < 4; ks++) {
            bf16x8 pa = *(const bf16x8*)&Pl[(m0 + lr) * 136 + ks * 32 + lq * 8];
            bf16x8 v0 = *(const bf16x8*)&Vt[lr * 264 + ks * 32 + lq * 8];
            bf16x8 v1f = *(const bf16x8*)&Vt[(lr + 16) * 264 + ks * 32 + lq * 8];
            y0 = __builtin_amdgcn_mfma_f32_16x16x32_bf16(pa, v0, y0, 0, 0, 0);
            y1 = __builtin_amdgcn_mfma_f32_16x16x32_bf16(pa, v1f, y1, 0, 0, 0);
        }
        #pragma unroll
        for (int jt = 8; jt < 15; jt++)
            #pragma unroll
            for (int r = 0; r < 4; r++)
                Pl[(m0 + lq * 4 + r) * 136 + (jt - 8) * 16 + lr] = f2b(d[jt][r] * inv[r]);
        #pragma unroll
        for (int r = 0; r < 4; r++)
            Pl[(m0 + lq * 4 + r) * 136 + 112 + lr] = 0;
        #pragma unroll
        for (int ks = 0; ks < 4; ks++) {
            bf16x8 pa = *(const bf16x8*)&Pl[(m0 + lr) * 136 + ks * 32 + lq * 8];
            bf16x8 v0 = *(const bf16x8*)&Vt[lr * 264 + (ks + 4) * 32 + lq * 8];
            bf16x8 v1f = *(const bf16x8*)&Vt[(lr + 16) * 264 + (ks + 4) * 32 + lq * 8];
            y0 = __builtin_amdgcn_mfma_f32_16x16x32_bf16(pa, v0, y0, 0, 0, 0);
            y1 = __builtin_amdgcn_mfma_f32_16x16x32_bf16(pa, v1f, y1, 0, 0, 0);
        }
        #pragma unroll
        for (int r = 0; r < 4; r++) {
            int tok = rbase + lq * 4 + r;
            size_t oa = obase + (size_t)tok * 5040;
            outp[oa + lr] = f2b(y0[r]);
            if (lr < 5) outp[oa + 16 + lr] = f2b(y1[r]);
        }
    }
}

// -------- K2: axial stage 1 (tokens along w). grid = 1920 --------
__global__ __launch_bounds__(256) void k_ax1(const unsigned short* __restrict__ xp,
                                             unsigned short* __restrict__ qt,
                                             unsigned short* __restrict__ v1) {
    __shared__ __align__(16) unsigned short Q[240 * 40];
    __shared__ __align__(16) unsigned short Vt[32 * 264];
    __shared__ __align__(16) unsigned short Pl[64 * 136];
    int b = blockIdx.x / 240, h = blockIdx.x % 240;
    int tid = threadIdx.x;
    for (int i = tid; i < 4800; i += 256) ((unsigned int*)Q)[i] = 0;
    for (int i = tid; i < 4224; i += 256) ((unsigned int*)Vt)[i] = 0;
    __syncthreads();
    size_t xb = (size_t)b * HWSZ + h * 240;
    for (int idx = tid; idx < 5040; idx += 256) {
        int c = idx / 240, w = idx - c * 240;
        Q[w * 40 + c]   = xp[(size_t)(84 + c) * NPIX + xb + w];
        Vt[c * 264 + w] = xp[(size_t)(105 + c) * NPIX + xb + w];
    }
    __syncthreads();
    size_t qtb = (size_t)b * 1209600 + h * 21;
    for (int idx = tid; idx < 5040; idx += 256) {
        int w = idx / 21, c = idx - w * 21;
        qt[qtb + (size_t)w * 5040 + c] = Q[w * 40 + c];
    }
    axial_core(Q, Vt, Pl, v1, (size_t)b * 1209600 + h * 21);
}

// -------- K3: axial stage 2 (tokens along h). grid = 1920 --------
__global__ __launch_bounds__(256) void k_ax2(const unsigned short* __restrict__ qt,
                                             const unsigned short* __restrict__ v1,
                                             unsigned short* __restrict__ ybB) {
    __shared__ __align__(16) unsigned short Q[240 * 40];
    __shared__ __align__(16) unsigned short Vt[32 * 264];
    __shared__ __align__(16) unsigned short Pl[64 * 136];
    int b = blockIdx.x / 240, w = blockIdx.x % 240;
    int tid = threadIdx.x;
    for (int i = tid; i < 4800; i += 256) ((unsigned int*)Q)[i] = 0;
    for (int i = tid; i < 4224; i += 256) ((unsigned int*)Vt)[i] = 0;
    __syncthreads();
    size_t base = ((size_t)b * 240 + w) * 5040;
    for (int idx = tid; idx < 5040; idx += 256) {
        int h = idx / 21, c = idx - h * 21;
        Q[h * 40 + c]   = qt[base + idx];
        Vt[c * 264 + h] = v1[base + idx];
    }
    __syncthreads();
    axial_core(Q, Vt, Pl, ybB, (size_t)b * 1209600 + w * 21);
}

// -------- K4: conv_out --------
__global__ __launch_bounds__(256) void k_out(const unsigned short* __restrict__ ybA,
                                             const unsigned short* __restrict__ ybB,
                                             const float* __restrict__ w_out,
                                             const float* __restrict__ b_out,
                                             float* __restrict__ out) {
    int p = blockIdx.x * 256 + threadIdx.x;
    if (p >= NPIX) return;
    int b = p / HWSZ;
    int hw = p - b * HWSZ;
    float yr[63];
    const unsigned short* a = ybA + (size_t)p * 42;
    #pragma unroll
    for (int c = 0; c < 42; c++) yr[c] = b2f(a[c]);
    const unsigned short* bb = ybB + (size_t)p * 21;
    #pragma unroll
    for (int c = 0; c < 21; c++) yr[42 + c] = b2f(bb[c]);
    #pragma unroll 1
    for (int o = 0; o < 63; o++) {
        float acc = b_out[o];
        const float* wr = &w_out[o * 63];
        #pragma unroll
        for (int c = 0; c < 63; c++) acc += wr[c] * yr[c];
        out[((size_t)(b * 63 + o)) * HWSZ + hw] = acc;
    }
}

extern "C" void kernel_launch(void* const* d_in, const int* in_sizes, int n_in,
                              void* d_out, int out_size, void* d_ws, size_t ws_size,
                              hipStream_t stream) {
    const float* x     = (const float*)d_in[0];
    const float* w_in  = (const float*)d_in[1];
    const float* b_in  = (const float*)d_in[2];
    const float* gamma = (const float*)d_in[3];
    const float* beta  = (const float*)d_in[4];
    const float* mean  = (const float*)d_in[5];
    const float* var   = (const float*)d_in[6];
    const float* w_out = (const float*)d_in[7];
    const float* b_out = (const float*)d_in[8];
    float* out = (float*)d_out;

    char* ws = (char*)d_ws;
    unsigned short* xp  = (unsigned short*)ws;                 // bf16 [126][NPIX]
    unsigned short* ybA = (unsigned short*)(ws + 116121600);   // bf16 [NPIX][42]
    float* Weff = (float*)(ws + 154828800);
    float* beff = (float*)(ws + 154861568);
    unsigned short* qt  = (unsigned short*)ws;                 // alias xp ch 0..62 (dead after k_win)
    unsigned short* v1  = (unsigned short*)(ws + 19353600);
    unsigned short* ybB = (unsigned short*)(ws + 38707200);

    k_prep <<<32, 256, 0, stream>>>(w_in, b_in, gamma, beta, mean, var, Weff, beff);
    k_projM<<<1800, 256, 0, stream>>>(x, Weff, beff, xp);
    k_win  <<<9216, 256, 0, stream>>>(xp, ybA);
    k_ax1  <<<1920, 256, 0, stream>>>(xp, qt, v1);
    k_ax2  <<<1920, 256, 0, stream>>>(qt, v1, ybB);
    k_out  <<<1800, 256, 0, stream>>>(ybA, ybB, w_out, b_out, out);
}

// Round 6
// 348.708 us; speedup vs baseline: 5.6233x; 1.3457x over previous
//
#include <hip/hip_runtime.h>
#include <math.h>

#define HWSZ  57600
#define NPIX  460800   // 8*57600

typedef __attribute__((ext_vector_type(8))) short bf16x8;
typedef __attribute__((ext_vector_type(4))) float f32x4;
typedef __attribute__((ext_vector_type(16))) float f32x16;

__device__ __forceinline__ unsigned short f2b(float f) {
    unsigned int u = __float_as_uint(f);
    unsigned int r = (u + 0x7FFFu + ((u >> 16) & 1u)) >> 16;
    return (unsigned short)r;
}
__device__ __forceinline__ float b2f(unsigned short s) {
    return __uint_as_float(((unsigned int)s) << 16);
}

// -------- K0: fold BN into conv_in weights --------
__global__ void k_prep(const float* __restrict__ w_in, const float* __restrict__ b_in,
                       const float* __restrict__ gamma, const float* __restrict__ beta,
                       const float* __restrict__ mean,  const float* __restrict__ var,
                       float* __restrict__ Weff, float* __restrict__ beff) {
    int idx = blockIdx.x * 256 + threadIdx.x;
    if (idx < 7938) {
        int o = idx / 63;
        float s = gamma[o] * rsqrtf(var[o] + 1e-5f);
        Weff[idx] = w_in[idx] * s;
    } else if (idx < 8064) {
        int o = idx - 7938;
        float s = gamma[o] * rsqrtf(var[o] + 1e-5f);
        beff[o] = b_in[o] * s + beta[o] - mean[o] * s;
    }
}

// -------- K_proj (MFMA): xp[o][p] = sum_c Weff[o][c] * x[c][p] + beff[o] --------
#define XS 66
#define WSTR 66
__global__ __launch_bounds__(256) void k_projM(const float* __restrict__ x,
                                               const float* __restrict__ Weff,
                                               const float* __restrict__ beff,
                                               unsigned short* __restrict__ xp) {
    __shared__ __align__(16) unsigned short Xl[256 * XS];
    __shared__ __align__(16) unsigned short Wl[128 * WSTR];
    __shared__ float bl[128];
    int blk = blockIdx.x;
    int tid = threadIdx.x;
    int b = blk / 225;
    int hw0 = (blk - b * 225) * 256;
    int wv = tid >> 6, l = tid & 63;
    int lr = l & 15, lq = l >> 4;
    const f32x4 zf = {0.f, 0.f, 0.f, 0.f};

    {
        const float* xb = x + (size_t)b * 63 * HWSZ + hw0 + tid;
        unsigned short* xr = &Xl[tid * XS];
        #pragma unroll
        for (int c = 0; c < 62; c += 2) {
            unsigned int lo = f2b(xb[(size_t)c * HWSZ]);
            unsigned int hi = f2b(xb[(size_t)(c + 1) * HWSZ]);
            *(unsigned int*)&xr[c] = lo | (hi << 16);
        }
        unsigned int lo = f2b(xb[(size_t)62 * HWSZ]);
        *(unsigned int*)&xr[62] = lo;
    }
    for (int idx = tid; idx < 7938; idx += 256) {
        int o = idx / 63, c = idx - o * 63;
        Wl[o * WSTR + c] = f2b(Weff[idx]);
    }
    for (int idx = tid; idx < 128; idx += 256) {
        Wl[idx * WSTR + 63] = 0;
        bl[idx] = (idx < 126) ? beff[idx] : 0.f;
    }
    for (int idx = tid; idx < 128; idx += 256) Wl[(126 + (idx >> 6)) * WSTR + (idx & 63)] = 0;
    __syncthreads();

    bf16x8 wa[8][2];
    #pragma unroll
    for (int ot = 0; ot < 8; ot++)
        #pragma unroll
        for (int ks = 0; ks < 2; ks++)
            wa[ot][ks] = *(const bf16x8*)&Wl[(ot * 16 + lr) * WSTR + ks * 32 + lq * 8];

    for (int pt = 0; pt < 4; pt++) {
        int prow = (wv * 4 + pt) * 16;
        bf16x8 xb0 = *(const bf16x8*)&Xl[(prow + lr) * XS + lq * 8];
        bf16x8 xb1 = *(const bf16x8*)&Xl[(prow + lr) * XS + 32 + lq * 8];
        f32x4 acc[8];
        #pragma unroll
        for (int ot = 0; ot < 8; ot++) {
            acc[ot] = __builtin_amdgcn_mfma_f32_16x16x32_bf16(wa[ot][0], xb0, zf, 0, 0, 0);
            acc[ot] = __builtin_amdgcn_mfma_f32_16x16x32_bf16(wa[ot][1], xb1, acc[ot], 0, 0, 0);
        }
        size_t pbase = (size_t)b * HWSZ + hw0 + prow + lr;
        #pragma unroll
        for (int ot = 0; ot < 8; ot++) {
            #pragma unroll
            for (int r = 0; r < 4; r++) {
                int o = ot * 16 + lq * 4 + r;
                if (o < 126)
                    xp[(size_t)o * NPIX + pbase] = f2b(acc[ot][r] + bl[o]);
            }
        }
    }
}

// -------- K1 (MFMA): window attention, 1 wave = 1 window (32x32x16, pad 25->32) --------
// grid = 2 branches * 8 b * 48 wi * 12 col-groups = 9216
__global__ __launch_bounds__(256) void k_winM(const unsigned short* __restrict__ xp,
                                              unsigned short* __restrict__ ybA) {
    // QP: Q then overwritten by P (wave-private reuse). Vt: [ch][tok].
    __shared__ __align__(16) unsigned short QP[4][32][40];
    __shared__ __align__(16) unsigned short Vtl[4][32][40];
    int bid = blockIdx.x;
    int branch = bid / 4608;
    int r = bid - branch * 4608;
    int b = r / 576;
    int r2 = r - b * 576;
    int wi = r2 / 12;
    int g = r2 - wi * 12;
    int tid = threadIdx.x;
    int wv = tid >> 6, l = tid & 63;
    int ish = branch ? 3 : 0;
    int osh = branch ? 2 : 0;

    for (int i = tid; i < 2560; i += 256) ((unsigned int*)QP)[i] = 0;
    for (int i = tid; i < 2560; i += 256) ((unsigned int*)Vtl)[i] = 0;
    __syncthreads();

    size_t xbase = (size_t)b * HWSZ;
    for (int idx = tid; idx < 4200; idx += 256) {
        int ch = idx / 100, p100 = idx - ch * 100;
        int pr = p100 / 20, pc20 = p100 - pr * 20;
        int w = pc20 / 5, tok = pr * 5 + (pc20 - w * 5);
        int ih = (wi * 5 + pr + ish) % 240;
        int iw = (g * 20 + pc20 + ish) % 240;
        unsigned short v = xp[(size_t)(branch * 42 + ch) * NPIX + xbase + ih * 240 + iw];
        if (ch < 21) QP[w][tok][ch] = v;
        else         Vtl[w][ch - 21][tok] = v;
    }
    __syncthreads();

    int lr32 = l & 31, hi = l >> 5;
    f32x16 z16;
    #pragma unroll
    for (int i = 0; i < 16; i++) z16[i] = 0.f;

    // S = Q Q^T  (A and B both = Q rows; K=32 in two steps)
    bf16x8 a0 = *(const bf16x8*)&QP[wv][lr32][hi * 8];
    bf16x8 a1 = *(const bf16x8*)&QP[wv][lr32][16 + hi * 8];
    f32x16 S = __builtin_amdgcn_mfma_f32_32x32x16_bf16(a0, a0, z16, 0, 0, 0);
    S = __builtin_amdgcn_mfma_f32_32x32x16_bf16(a1, a1, S, 0, 0, 0);

    // softmax over cols (col = lr32, valid < 25); rows independent per reg
    bool colok = (lr32 < 25);
    float p[16];
    #pragma unroll
    for (int rg = 0; rg < 16; rg++) {
        float v = colok ? S[rg] : -1e30f;
        float m = v;
        #pragma unroll
        for (int s2 = 1; s2 < 32; s2 <<= 1) m = fmaxf(m, __shfl_xor(m, s2));
        float e = colok ? __expf(S[rg] - m) : 0.f;
        float su = e;
        #pragma unroll
        for (int s2 = 1; s2 < 32; s2 <<= 1) su += __shfl_xor(su, s2);
        p[rg] = e / su;
    }
    // P -> LDS (overwrite own Q stripe; Q already consumed into a0/a1)
    #pragma unroll
    for (int rg = 0; rg < 16; rg++) {
        int row = (rg & 3) + 8 * (rg >> 2) + 4 * hi;
        QP[wv][row][lr32] = f2b(p[rg]);
    }

    // Y = P V   (B rows = Vt[ch][tok])
    bf16x8 pa0 = *(const bf16x8*)&QP[wv][lr32][hi * 8];
    bf16x8 pa1 = *(const bf16x8*)&QP[wv][lr32][16 + hi * 8];
    bf16x8 vb0 = *(const bf16x8*)&Vtl[wv][lr32][hi * 8];
    bf16x8 vb1 = *(const bf16x8*)&Vtl[wv][lr32][16 + hi * 8];
    f32x16 Y = __builtin_amdgcn_mfma_f32_32x32x16_bf16(pa0, vb0, z16, 0, 0, 0);
    Y = __builtin_amdgcn_mfma_f32_32x32x16_bf16(pa1, vb1, Y, 0, 0, 0);

    if (lr32 < 21) {
        #pragma unroll
        for (int rg = 0; rg < 16; rg++) {
            int tok = (rg & 3) + 8 * (rg >> 2) + 4 * hi;
            if (tok < 25) {
                int pr = tok / 5, pc = tok - pr * 5;
                int oh = (wi * 5 + pr + osh) % 240;
                int ow = (g * 20 + wv * 5 + pc + osh) % 240;
                ybA[((size_t)b * HWSZ + oh * 240 + ow) * 42 + branch * 21 + lr32] = f2b(Y[rg]);
            }
        }
    }
}

// -------- MFMA axial attention core (verified round 4) --------
__device__ __forceinline__ void axial_core(const unsigned short* Q, const unsigned short* Vt,
                                           unsigned short* Pl,
                                           unsigned short* outp, size_t obase) {
    int tid = threadIdx.x;
    int wv = tid >> 6, l = tid & 63;
    int lr = l & 15, lq = l >> 4;
    const f32x4 zf = {0.f, 0.f, 0.f, 0.f};
    int m0 = wv * 16;

    for (int mt = 0; mt < 4; mt++) {
        if (mt == 3 && wv == 3) continue;   // tile 15 would be rows 240..255 (OOB)
        int rbase = mt * 64 + wv * 16;
        bf16x8 afr = *(const bf16x8*)&Q[(rbase + lr) * 40 + lq * 8];
        f32x4 d[15];
        #pragma unroll
        for (int jt = 0; jt < 15; jt++) {
            bf16x8 bfr = *(const bf16x8*)&Q[(jt * 16 + lr) * 40 + lq * 8];
            d[jt] = __builtin_amdgcn_mfma_f32_16x16x32_bf16(afr, bfr, zf, 0, 0, 0);
        }
        float mx[4] = {-1e30f, -1e30f, -1e30f, -1e30f};
        #pragma unroll
        for (int jt = 0; jt < 15; jt++)
            #pragma unroll
            for (int r = 0; r < 4; r++) mx[r] = fmaxf(mx[r], d[jt][r]);
        #pragma unroll
        for (int s = 1; s < 16; s <<= 1)
            #pragma unroll
            for (int r = 0; r < 4; r++) mx[r] = fmaxf(mx[r], __shfl_xor(mx[r], s));
        float sm[4] = {0.f, 0.f, 0.f, 0.f};
        #pragma unroll
        for (int jt = 0; jt < 15; jt++)
            #pragma unroll
            for (int r = 0; r < 4; r++) { float e = __expf(d[jt][r] - mx[r]); d[jt][r] = e; sm[r] += e; }
        #pragma unroll
        for (int s = 1; s < 16; s <<= 1)
            #pragma unroll
            for (int r = 0; r < 4; r++) sm[r] += __shfl_xor(sm[r], s);
        float inv[4];
        #pragma unroll
        for (int r = 0; r < 4; r++) inv[r] = 1.0f / sm[r];

        #pragma unroll
        for (int jt = 0; jt < 8; jt++)
            #pragma unroll
            for (int r = 0; r < 4; r++)
                Pl[(m0 + lq * 4 + r) * 136 + jt * 16 + lr] = f2b(d[jt][r] * inv[r]);
        f32x4 y0 = zf, y1 = zf;
        #pragma unroll
        for (int ks = 0; ks < 4; ks++) {
            bf16x8 pa = *(const bf16x8*)&Pl[(m0 + lr) * 136 + ks * 32 + lq * 8];
            bf16x8 v0 = *(const bf16x8*)&Vt[lr * 264 + ks * 32 + lq * 8];
            bf16x8 v1f = *(const bf16x8*)&Vt[(lr + 16) * 264 + ks * 32 + lq * 8];
            y0 = __builtin_amdgcn_mfma_f32_16x16x32_bf16(pa, v0, y0, 0, 0, 0);
            y1 = __builtin_amdgcn_mfma_f32_16x16x32_bf16(pa, v1f, y1, 0, 0, 0);
        }
        #pragma unroll
        for (int jt = 8; jt < 15; jt++)
            #pragma unroll
            for (int r = 0; r < 4; r++)
                Pl[(m0 + lq * 4 + r) * 136 + (jt - 8) * 16 + lr] = f2b(d[jt][r] * inv[r]);
        #pragma unroll
        for (int r = 0; r < 4; r++)
            Pl[(m0 + lq * 4 + r) * 136 + 112 + lr] = 0;
        #pragma unroll
        for (int ks = 0; ks < 4; ks++) {
            bf16x8 pa = *(const bf16x8*)&Pl[(m0 + lr) * 136 + ks * 32 + lq * 8];
            bf16x8 v0 = *(const bf16x8*)&Vt[lr * 264 + (ks + 4) * 32 + lq * 8];
            bf16x8 v1f = *(const bf16x8*)&Vt[(lr + 16) * 264 + (ks + 4) * 32 + lq * 8];
            y0 = __builtin_amdgcn_mfma_f32_16x16x32_bf16(pa, v0, y0, 0, 0, 0);
            y1 = __builtin_amdgcn_mfma_f32_16x16x32_bf16(pa, v1f, y1, 0, 0, 0);
        }
        #pragma unroll
        for (int r = 0; r < 4; r++) {
            int tok = rbase + lq * 4 + r;
            size_t oa = obase + (size_t)tok * 5040;
            outp[oa + lr] = f2b(y0[r]);
            if (lr < 5) outp[oa + 16 + lr] = f2b(y1[r]);
        }
    }
}

// -------- K2: axial stage 1 (tokens along w). grid = 1920 --------
__global__ __launch_bounds__(256) void k_ax1(const unsigned short* __restrict__ xp,
                                             unsigned short* __restrict__ qt,
                                             unsigned short* __restrict__ v1) {
    __shared__ __align__(16) unsigned short Q[240 * 40];
    __shared__ __align__(16) unsigned short Vt[32 * 264];
    __shared__ __align__(16) unsigned short Pl[64 * 136];
    int b = blockIdx.x / 240, h = blockIdx.x % 240;
    int tid = threadIdx.x;
    for (int i = tid; i < 4800; i += 256) ((unsigned int*)Q)[i] = 0;
    for (int i = tid; i < 4224; i += 256) ((unsigned int*)Vt)[i] = 0;
    __syncthreads();
    size_t xb = (size_t)b * HWSZ + h * 240;
    for (int idx = tid; idx < 5040; idx += 256) {
        int c = idx / 240, w = idx - c * 240;
        Q[w * 40 + c]   = xp[(size_t)(84 + c) * NPIX + xb + w];
        Vt[c * 264 + w] = xp[(size_t)(105 + c) * NPIX + xb + w];
    }
    __syncthreads();
    size_t qtb = (size_t)b * 1209600 + h * 21;
    for (int idx = tid; idx < 5040; idx += 256) {
        int w = idx / 21, c = idx - w * 21;
        qt[qtb + (size_t)w * 5040 + c] = Q[w * 40 + c];
    }
    axial_core(Q, Vt, Pl, v1, (size_t)b * 1209600 + h * 21);
}

// -------- K3: axial stage 2 (tokens along h). grid = 1920 --------
__global__ __launch_bounds__(256) void k_ax2(const unsigned short* __restrict__ qt,
                                             const unsigned short* __restrict__ v1,
                                             unsigned short* __restrict__ ybB) {
    __shared__ __align__(16) unsigned short Q[240 * 40];
    __shared__ __align__(16) unsigned short Vt[32 * 264];
    __shared__ __align__(16) unsigned short Pl[64 * 136];
    int b = blockIdx.x / 240, w = blockIdx.x % 240;
    int tid = threadIdx.x;
    for (int i = tid; i < 4800; i += 256) ((unsigned int*)Q)[i] = 0;
    for (int i = tid; i < 4224; i += 256) ((unsigned int*)Vt)[i] = 0;
    __syncthreads();
    size_t base = ((size_t)b * 240 + w) * 5040;
    for (int idx = tid; idx < 5040; idx += 256) {
        int h = idx / 21, c = idx - h * 21;
        Q[h * 40 + c]   = qt[base + idx];
        Vt[c * 264 + h] = v1[base + idx];
    }
    __syncthreads();
    axial_core(Q, Vt, Pl, ybB, (size_t)b * 1209600 + w * 21);
}

// -------- K4 (MFMA): conv_out. M=64 out-ch, N=256 px, K=64 --------
__global__ __launch_bounds__(256) void k_outM(const unsigned short* __restrict__ ybA,
                                              const unsigned short* __restrict__ ybB,
                                              const float* __restrict__ w_out,
                                              const float* __restrict__ b_out,
                                              float* __restrict__ out) {
    __shared__ __align__(16) unsigned short Yl[256][72];
    __shared__ __align__(16) unsigned short Wo[64][72];
    __shared__ float bl[64];
    int tid = threadIdx.x;
    int pg = blockIdx.x * 256 + tid;

    for (int i = tid; i < 64 * 36; i += 256) ((unsigned int*)Wo)[i] = 0;
    __syncthreads();
    {
        const unsigned int* a32 = (const unsigned int*)(ybA + (size_t)pg * 42);
        unsigned short* yr = Yl[tid];
        #pragma unroll
        for (int c = 0; c < 21; c++) *(unsigned int*)&yr[c * 2] = a32[c];
        const unsigned short* bb2 = ybB + (size_t)pg * 21;
        #pragma unroll
        for (int c = 0; c < 21; c++) yr[42 + c] = bb2[c];
        #pragma unroll
        for (int c = 63; c < 72; c++) yr[c] = 0;
    }
    for (int idx = tid; idx < 3969; idx += 256) {
        int o = idx / 63, c = idx - o * 63;
        Wo[o][c] = f2b(w_out[idx]);
    }
    if (tid < 64) bl[tid] = (tid < 63) ? b_out[tid] : 0.f;
    __syncthreads();

    int wv = tid >> 6, l = tid & 63;
    int lr = l & 15, lq = l >> 4;
    const f32x4 zf = {0.f, 0.f, 0.f, 0.f};
    bf16x8 wa[4][2];
    #pragma unroll
    for (int ot = 0; ot < 4; ot++)
        #pragma unroll
        for (int ks = 0; ks < 2; ks++)
            wa[ot][ks] = *(const bf16x8*)&Wo[ot * 16 + lr][ks * 32 + lq * 8];

    int p0 = blockIdx.x * 256;
    int b = p0 / HWSZ;
    int hwb = p0 - b * HWSZ;
    for (int pt = 0; pt < 4; pt++) {
        int prow = (wv * 4 + pt) * 16;
        bf16x8 y0 = *(const bf16x8*)&Yl[prow + lr][lq * 8];
        bf16x8 y1 = *(const bf16x8*)&Yl[prow + lr][32 + lq * 8];
        f32x4 acc[4];
        #pragma unroll
        for (int ot = 0; ot < 4; ot++) {
            acc[ot] = __builtin_amdgcn_mfma_f32_16x16x32_bf16(wa[ot][0], y0, zf, 0, 0, 0);
            acc[ot] = __builtin_amdgcn_mfma_f32_16x16x32_bf16(wa[ot][1], y1, acc[ot], 0, 0, 0);
        }
        int hw = hwb + prow + lr;
        #pragma unroll
        for (int ot = 0; ot < 4; ot++) {
            #pragma unroll
            for (int r = 0; r < 4; r++) {
                int o = ot * 16 + lq * 4 + r;
                if (o < 63)
                    out[((size_t)(b * 63 + o)) * HWSZ + hw] = acc[ot][r] + bl[o];
            }
        }
    }
}

extern "C" void kernel_launch(void* const* d_in, const int* in_sizes, int n_in,
                              void* d_out, int out_size, void* d_ws, size_t ws_size,
                              hipStream_t stream) {
    const float* x     = (const float*)d_in[0];
    const float* w_in  = (const float*)d_in[1];
    const float* b_in  = (const float*)d_in[2];
    const float* gamma = (const float*)d_in[3];
    const float* beta  = (const float*)d_in[4];
    const float* mean  = (const float*)d_in[5];
    const float* var   = (const float*)d_in[6];
    const float* w_out = (const float*)d_in[7];
    const float* b_out = (const float*)d_in[8];
    float* out = (float*)d_out;

    char* ws = (char*)d_ws;
    unsigned short* xp  = (unsigned short*)ws;                 // bf16 [126][NPIX]
    unsigned short* ybA = (unsigned short*)(ws + 116121600);   // bf16 [NPIX][42]
    float* Weff = (float*)(ws + 154828800);
    float* beff = (float*)(ws + 154861568);
    unsigned short* qt  = (unsigned short*)ws;                 // alias xp ch 0..62 (dead after k_win)
    unsigned short* v1  = (unsigned short*)(ws + 19353600);
    unsigned short* ybB = (unsigned short*)(ws + 38707200);

    k_prep <<<32, 256, 0, stream>>>(w_in, b_in, gamma, beta, mean, var, Weff, beff);
    k_projM<<<1800, 256, 0, stream>>>(x, Weff, beff, xp);
    k_winM <<<9216, 256, 0, stream>>>(xp, ybA);
    k_ax1  <<<1920, 256, 0, stream>>>(xp, qt, v1);
    k_ax2  <<<1920, 256, 0, stream>>>(qt, v1, ybB);
    k_outM <<<1800, 256, 0, stream>>>(ybA, ybB, w_out, b_out, out);
}